// Round 1
// baseline (91.727 us; speedup 1.0000x reference)
//
#include <hip/hip_runtime.h>

// CustomLSTM: T=262144 independent timesteps (h0=c0=0 each step).
//   gates = x @ W_ih^T + (b_ih + b_hh); i,f,g,o = split(gates)  [f unused: f*c0=0]
//   c = sigmoid(i)*tanh(g); h = sigmoid(o)*tanh(c)
//   out = sigmoid(h @ W_lin^T + b_lin)
// VALU/transcendental-bound: ~950 FMA + ~200 exp/rcp per row.

#define T_TOTAL 262144
#define HID 50
#define INPD 6
// packed LDS record per hidden unit j: wi[6], wg[6], wo[6], bi, bg, bo, wlin  (22 floats, pad to 24 for 16B-aligned float4 reads)
#define WREC 24

__device__ __forceinline__ float fexp2(float x) {
#if __has_builtin(__builtin_amdgcn_exp2f)
    return __builtin_amdgcn_exp2f(x);
#else
    return exp2f(x);
#endif
}
__device__ __forceinline__ float frcp(float x) {
#if __has_builtin(__builtin_amdgcn_rcpf)
    return __builtin_amdgcn_rcpf(x);
#else
    return 1.0f / x;
#endif
}

#define LOG2E 1.4426950408889634f

__device__ __forceinline__ float fsig(float x) {
    // sigmoid(x) = 1/(1+exp(-x));  exp(-x) = 2^(-x*log2e)
    return frcp(1.0f + fexp2(-LOG2E * x));
}
__device__ __forceinline__ float ftanh(float x) {
    // tanh(x) = 1 - 2/(exp(2x)+1); saturates cleanly (rcp(inf)=0)
    return 1.0f - 2.0f * frcp(1.0f + fexp2(2.0f * LOG2E * x));
}

__global__ __launch_bounds__(256) void lstm_fused_kernel(
    const float* __restrict__ x,      // [T,6]
    const float* __restrict__ W_ih,   // [200,6] rows: 0..49 i, 50..99 f, 100..149 g, 150..199 o
    const float* __restrict__ b_ih,   // [200]
    const float* __restrict__ b_hh,   // [200]
    const float* __restrict__ W_lin,  // [50]
    const float* __restrict__ b_lin,  // [1]
    float* __restrict__ out)          // [T]
{
    __shared__ __align__(16) float wbuf[HID * WREC];

    const int tid = threadIdx.x;

    // Stage packed weights: 50 units x 22 live floats (i,g,o rows + combined bias + wlin)
    for (int p = tid; p < HID * 22; p += 256) {
        const int j = p / 22;
        const int s = p - j * 22;
        float v;
        if (s < 6)        v = W_ih[j * 6 + s];                       // wi
        else if (s < 12)  v = W_ih[(100 + j) * 6 + (s - 6)];         // wg
        else if (s < 18)  v = W_ih[(150 + j) * 6 + (s - 12)];        // wo
        else if (s == 18) v = b_ih[j]       + b_hh[j];               // bi
        else if (s == 19) v = b_ih[100 + j] + b_hh[100 + j];         // bg
        else if (s == 20) v = b_ih[150 + j] + b_hh[150 + j];         // bo
        else              v = W_lin[j];                              // wlin
        wbuf[j * WREC + s] = v;
    }
    __syncthreads();

    // 2 rows per thread, coalesced: row0 = blk*512 + tid, row1 = row0 + 256
    const int row0 = blockIdx.x * 512 + tid;
    const int row1 = row0 + 256;

    const float2* x2 = (const float2*)x;   // rows are 24B (8B-aligned): 3 float2 per row
    float2 pa0 = x2[3 * row0], pa1 = x2[3 * row0 + 1], pa2 = x2[3 * row0 + 2];
    float2 pb0 = x2[3 * row1], pb1 = x2[3 * row1 + 1], pb2 = x2[3 * row1 + 2];
    const float xa0 = pa0.x, xa1 = pa0.y, xa2 = pa1.x, xa3 = pa1.y, xa4 = pa2.x, xa5 = pa2.y;
    const float xb0 = pb0.x, xb1 = pb0.y, xb2 = pb1.x, xb3 = pb1.y, xb4 = pb2.x, xb5 = pb2.y;

    float acc0 = 0.0f, acc1 = 0.0f;

    #pragma unroll 5
    for (int j = 0; j < HID; ++j) {
        const float4* w4 = (const float4*)(&wbuf[j * WREC]);
        const float4 A = w4[0];  // wi0..wi3
        const float4 B = w4[1];  // wi4,wi5,wg0,wg1
        const float4 C = w4[2];  // wg2..wg5
        const float4 D = w4[3];  // wo0..wo3
        const float4 E = w4[4];  // wo4,wo5,bi,bg
        const float4 F = w4[5];  // bo,wlin,pad,pad

        // row0
        {
            float gi = E.z + A.x*xa0 + A.y*xa1 + A.z*xa2 + A.w*xa3 + B.x*xa4 + B.y*xa5;
            float gg = E.w + B.z*xa0 + B.w*xa1 + C.x*xa2 + C.y*xa3 + C.z*xa4 + C.w*xa5;
            float go = F.x + D.x*xa0 + D.y*xa1 + D.z*xa2 + D.w*xa3 + E.x*xa4 + E.y*xa5;
            float c = fsig(gi) * ftanh(gg);
            float h = fsig(go) * ftanh(c);
            acc0 += h * F.y;
        }
        // row1
        {
            float gi = E.z + A.x*xb0 + A.y*xb1 + A.z*xb2 + A.w*xb3 + B.x*xb4 + B.y*xb5;
            float gg = E.w + B.z*xb0 + B.w*xb1 + C.x*xb2 + C.y*xb3 + C.z*xb4 + C.w*xb5;
            float go = F.x + D.x*xb0 + D.y*xb1 + D.z*xb2 + D.w*xb3 + E.x*xb4 + E.y*xb5;
            float c = fsig(gi) * ftanh(gg);
            float h = fsig(go) * ftanh(c);
            acc1 += h * F.y;
        }
    }

    const float bl = b_lin[0];
    out[row0] = fsig(acc0 + bl);
    out[row1] = fsig(acc1 + bl);
}

extern "C" void kernel_launch(void* const* d_in, const int* in_sizes, int n_in,
                              void* d_out, int out_size, void* d_ws, size_t ws_size,
                              hipStream_t stream) {
    const float* x     = (const float*)d_in[0];  // [262144,6]
    const float* W_ih  = (const float*)d_in[1];  // [200,6]
    const float* b_ih  = (const float*)d_in[2];  // [200]
    // d_in[3] = W_hh [200,50] — mathematically unused (h0 = 0)
    const float* b_hh  = (const float*)d_in[4];  // [200]
    const float* W_lin = (const float*)d_in[5];  // [50]
    const float* b_lin = (const float*)d_in[6];  // [1]
    float* out = (float*)d_out;

    // 512 rows per block (256 threads x 2 rows) -> 512 blocks exactly covers T=262144
    lstm_fused_kernel<<<dim3(T_TOTAL / 512), dim3(256), 0, stream>>>(
        x, W_ih, b_ih, b_hh, W_lin, b_lin, out);
}